// Round 1
// baseline (28.649 us; speedup 1.0000x reference)
//
#include <hip/hip_runtime.h>
#include <hip/hip_bf16.h>

#define MARGIN 0.1f
#define B 512
#define P 4
#define N 64
#define D 1024
#define NV (P + N)   // 68 score vectors per batch row

// One block per batch row b. 256 threads = 4 waves.
__global__ __launch_bounds__(256) void scores_kernel(
    const float* __restrict__ q,     // [B, D]
    const float* __restrict__ pos,   // [B, P, D]
    const float* __restrict__ neg,   // [B, N, D]
    float* __restrict__ partial)     // [B]
{
    const int b    = blockIdx.x;
    const int tid  = threadIdx.x;
    const int lane = tid & 63;
    const int wave = tid >> 6;       // 0..3

    // Each lane keeps 16 query floats (4 x float4). float4 index i*64+lane:
    // 16B/lane x 64 lanes contiguous -> 1KB coalesced per load.
    const float4* q4 = (const float4*)(q + (size_t)b * D);
    float4 qv[4];
#pragma unroll
    for (int i = 0; i < 4; ++i) qv[i] = q4[i * 64 + lane];

    __shared__ float scores[NV];     // [0..3]=pos, [4..67]=neg

    // 17 vectors per wave
    for (int v = wave; v < NV; v += 4) {
        const float* vec = (v < P)
            ? (pos + ((size_t)b * P + v) * D)
            : (neg + ((size_t)b * N + (v - P)) * D);
        const float4* v4 = (const float4*)vec;
        float acc = 0.0f;
#pragma unroll
        for (int i = 0; i < 4; ++i) {
            float4 x = v4[i * 64 + lane];
            acc += qv[i].x * x.x + qv[i].y * x.y + qv[i].z * x.z + qv[i].w * x.w;
        }
        // 64-lane wave reduction
#pragma unroll
        for (int off = 32; off > 0; off >>= 1)
            acc += __shfl_down(acc, off, 64);
        if (lane == 0) scores[v] = acc;
    }
    __syncthreads();

    // Pairwise: 4*64 = 256 pairs, exactly one per thread.
    // i = tid>>6 (pos index), j = tid&63 (neg index)
    float ps  = scores[tid >> 6];
    float ns  = scores[P + (tid & 63)];
    float val = MARGIN - ps + ns;
    val = val > 0.0f ? val : 0.0f;

    // block reduce
#pragma unroll
    for (int off = 32; off > 0; off >>= 1)
        val += __shfl_down(val, off, 64);

    __shared__ float wsum[4];
    if (lane == 0) wsum[wave] = val;
    __syncthreads();
    if (tid == 0)
        partial[b] = wsum[0] + wsum[1] + wsum[2] + wsum[3];
}

// Deterministic final reduction of the 512 per-block partials.
__global__ __launch_bounds__(512) void finalize_kernel(
    const float* __restrict__ partial, float* __restrict__ out)
{
    const int t    = threadIdx.x;
    const int lane = t & 63;
    const int w    = t >> 6;

    float v = partial[t];
#pragma unroll
    for (int off = 32; off > 0; off >>= 1)
        v += __shfl_down(v, off, 64);

    __shared__ float wsum[8];
    if (lane == 0) wsum[w] = v;
    __syncthreads();
    if (t == 0) {
        float s = 0.0f;
#pragma unroll
        for (int i = 0; i < 8; ++i) s += wsum[i];
        out[0] = s / (float)(B * P * N);
    }
}

extern "C" void kernel_launch(void* const* d_in, const int* in_sizes, int n_in,
                              void* d_out, int out_size, void* d_ws, size_t ws_size,
                              hipStream_t stream) {
    const float* q   = (const float*)d_in[0];   // [512,1024]
    const float* pos = (const float*)d_in[1];   // [512,4,1024]
    const float* neg = (const float*)d_in[2];   // [512,64,1024]
    float* out       = (float*)d_out;
    float* partial   = (float*)d_ws;            // 512 floats

    scores_kernel<<<B, 256, 0, stream>>>(q, pos, neg, partial);
    finalize_kernel<<<1, 512, 0, stream>>>(partial, out);
}

// Round 2
// 27.933 us; speedup vs baseline: 1.0256x; 1.0256x over previous
//
#include <hip/hip_runtime.h>
#include <hip/hip_bf16.h>

#define MARGIN 0.1f
#define B 512
#define P 4
#define N 64
#define D 1024
#define NV (P + N)   // 68 score vectors per batch row

// One block per batch row b. 1024 threads = 16 waves -> 32 waves/CU at
// 2 blocks/CU (max occupancy; this is a memory-latency-hiding play).
__global__ __launch_bounds__(1024) void scores_kernel(
    const float* __restrict__ q,     // [B, D]
    const float* __restrict__ pos,   // [B, P, D]
    const float* __restrict__ neg,   // [B, N, D]
    float* __restrict__ partial)     // [B]
{
    const int b    = blockIdx.x;
    const int tid  = threadIdx.x;
    const int lane = tid & 63;
    const int wave = tid >> 6;       // 0..15

    // Each lane keeps 16 query floats (4 x float4), coalesced 1KB/load.
    // All 16 waves read the same 4KB row -> L1-resident after first wave.
    const float4* q4 = (const float4*)(q + (size_t)b * D);
    float4 qv[4];
#pragma unroll
    for (int i = 0; i < 4; ++i) qv[i] = q4[i * 64 + lane];

    __shared__ float scores[NV];     // [0..3]=pos, [4..67]=neg

    // 68 vectors over 16 waves: waves 0-3 do 5, waves 4-15 do 4.
    for (int v = wave; v < NV; v += 16) {
        const float* vec = (v < P)
            ? (pos + ((size_t)b * P + v) * D)
            : (neg + ((size_t)b * N + (v - P)) * D);
        const float4* v4 = (const float4*)vec;
        float acc = 0.0f;
#pragma unroll
        for (int i = 0; i < 4; ++i) {
            float4 x = v4[i * 64 + lane];
            acc += qv[i].x * x.x + qv[i].y * x.y + qv[i].z * x.z + qv[i].w * x.w;
        }
        // 64-lane wave reduction
#pragma unroll
        for (int off = 32; off > 0; off >>= 1)
            acc += __shfl_down(acc, off, 64);
        if (lane == 0) scores[v] = acc;
    }
    __syncthreads();

    // Pairwise: 4*64 = 256 pairs on waves 0..3 (one pair per thread).
    __shared__ float wsum[4];
    if (wave < 4) {
        float ps  = scores[wave];            // pos index = tid>>6
        float ns  = scores[P + lane];        // neg index = tid&63
        float val = fmaxf(MARGIN - ps + ns, 0.0f);
#pragma unroll
        for (int off = 32; off > 0; off >>= 1)
            val += __shfl_down(val, off, 64);
        if (lane == 0) wsum[wave] = val;
    }
    __syncthreads();
    if (tid == 0)
        partial[b] = wsum[0] + wsum[1] + wsum[2] + wsum[3];
}

// Deterministic final reduction: one wave, 8 partials per lane, no syncs.
__global__ __launch_bounds__(64) void finalize_kernel(
    const float* __restrict__ partial, float* __restrict__ out)
{
    const int lane = threadIdx.x;
    float v = 0.0f;
#pragma unroll
    for (int k = 0; k < 8; ++k)
        v += partial[lane + 64 * k];
#pragma unroll
    for (int off = 32; off > 0; off >>= 1)
        v += __shfl_down(v, off, 64);
    if (lane == 0)
        out[0] = v / (float)(B * P * N);
}

extern "C" void kernel_launch(void* const* d_in, const int* in_sizes, int n_in,
                              void* d_out, int out_size, void* d_ws, size_t ws_size,
                              hipStream_t stream) {
    const float* q   = (const float*)d_in[0];   // [512,1024]
    const float* pos = (const float*)d_in[1];   // [512,4,1024]
    const float* neg = (const float*)d_in[2];   // [512,64,1024]
    float* out       = (float*)d_out;
    float* partial   = (float*)d_ws;            // 512 floats

    scores_kernel<<<B, 1024, 0, stream>>>(q, pos, neg, partial);
    finalize_kernel<<<1, 64, 0, stream>>>(partial, out);
}